// Round 7
// baseline (202.017 us; speedup 1.0000x reference)
//
#include <hip/hip_runtime.h>

#define PI_F 3.14159f
#define NQ 10
#define PB 64  // partial blocks for edge pooling

// ---------------- zero the accumulator region ----------------
__global__ void k_zero(float4* __restrict__ p, int n4) {
  int i = blockIdx.x * blockDim.x + threadIdx.x;
  int stride = gridDim.x * blockDim.x;
  float4 z = {0.f, 0.f, 0.f, 0.f};
  for (; i < n4; i += stride) p[i] = z;
}

// ---------------- dst-degree histogram (1 atomic/edge) ----------------
__global__ void k_count(const int* __restrict__ dstA, int E, int* __restrict__ cnt) {
  int e = blockIdx.x * blockDim.x + threadIdx.x;
  if (e < E) atomicAdd(&cnt[dstA[e]], 1);
}

// ---------------- edge-attr pooling: LDS bins + block partials ----------------
__global__ __launch_bounds__(1024) void k_edge_pool(const int* __restrict__ srcA,
                                                    const int* __restrict__ batch,
                                                    const float* __restrict__ eattr, int E,
                                                    float* __restrict__ part) {
  __shared__ float bins[1024 * 5];
  int t = threadIdx.x;
  for (int i = t; i < 5120; i += 1024) bins[i] = 0.f;
  __syncthreads();
  int per = (E + gridDim.x - 1) / gridDim.x;
  int base = blockIdx.x * per;
  int end = min(base + per, E);
  for (int e = base + t; e < end; e += 1024) {
    int s = srcA[e];
    int g = batch[s];
    float4 v = *(const float4*)(eattr + (size_t)e * 4);
    atomicAdd(&bins[g * 5 + 0], v.x);
    atomicAdd(&bins[g * 5 + 1], v.y);
    atomicAdd(&bins[g * 5 + 2], v.z);
    atomicAdd(&bins[g * 5 + 3], v.w);
    atomicAdd(&bins[g * 5 + 4], 1.0f);
  }
  __syncthreads();
  float* dst = part + (size_t)blockIdx.x * 5120;
  for (int i = t; i < 5120; i += 1024) dst[i] = bins[i];
}

// ---------------- scan level 1 ----------------
__global__ __launch_bounds__(1024) void k_scan1(const int* __restrict__ cnt,
                                                int* __restrict__ incl,
                                                int* __restrict__ bsum) {
  __shared__ int buf[1024];
  int t = threadIdx.x;
  int base = blockIdx.x << 10;
  buf[t] = cnt[base + t];
  __syncthreads();
#pragma unroll
  for (int off = 1; off < 1024; off <<= 1) {
    int x = (t >= off) ? buf[t - off] : 0;
    __syncthreads();
    buf[t] += x;
    __syncthreads();
  }
  incl[base + t] = buf[t];
  if (t == 1023) bsum[blockIdx.x] = buf[t];
}

// ---------------- node setup ----------------
__global__ void k_node_setup(const int* __restrict__ cnt, const int* __restrict__ incl,
                             const int* __restrict__ bsum, const int* __restrict__ batch,
                             int N, int Bn, int* __restrict__ rowStart,
                             int* __restrict__ pos, float* __restrict__ dinv,
                             float* __restrict__ invdeg, int* __restrict__ starts) {
  int i = blockIdx.x * blockDim.x + threadIdx.x;
  if (i >= N) return;
  int blk = i >> 10;
  int pre = 0;
  for (int j = 0; j < blk; j++) pre += bsum[j];
  int c = cnt[i];
  int inc = incl[i] + pre;
  rowStart[i + 1] = inc;
  pos[i] = inc - c;
  if (i == 0) rowStart[0] = 0;
  float d = (float)c + 1.0f;
  dinv[i] = 1.0f / sqrtf(d);
  invdeg[i] = 1.0f / d;
  int b = batch[i];
  int bp = (i == 0) ? -1 : batch[i - 1];
  for (int g = bp + 1; g <= b; g++) starts[g] = i;
  if (i == N - 1) {
    for (int g = b + 1; g <= Bn; g++) starts[g] = N;
  }
}

// ---------------- fill ----------------
__global__ void k_fill(const int* __restrict__ dst, const int* __restrict__ srcA,
                       const float* __restrict__ dinv, int E, int* __restrict__ pos,
                       int* __restrict__ srcSorted, float* __restrict__ dcoef) {
  int e = blockIdx.x * blockDim.x + threadIdx.x;
  if (e >= E) return;
  int s = srcA[e];
  int slot = atomicAdd(&pos[dst[e]], 1);
  srcSorted[slot] = s;
  dcoef[slot] = dinv[s];
}

// ---------------- fp32 tiled GEMM ----------------
__global__ __launch_bounds__(256) void k_gemm(const float* __restrict__ A,
                                              const float* __restrict__ B,
                                              float* __restrict__ C,
                                              int M, int K, int N) {
  __shared__ float As[64][36];
  __shared__ float Bs[32][68];
  int t = threadIdx.x;
  int tx = t & 15, ty = t >> 4;
  int row0 = blockIdx.y * 64, col0 = blockIdx.x * 64;
  float acc[4][4] = {};
  for (int k0 = 0; k0 < K; k0 += 32) {
#pragma unroll
    for (int rep = 0; rep < 2; rep++) {
      int slot = t + rep * 256;
      int r = slot >> 3;
      int cg = (slot & 7) << 2;
      float4 v = *(const float4*)(A + (size_t)(row0 + r) * K + (k0 + cg));
      *(float4*)&As[r][cg] = v;
      int r2 = slot >> 4;
      int cg2 = (slot & 15) << 2;
      float4 w = *(const float4*)(B + (size_t)(k0 + r2) * N + (col0 + cg2));
      *(float4*)&Bs[r2][cg2] = w;
    }
    __syncthreads();
#pragma unroll
    for (int kk = 0; kk < 32; kk++) {
      float av[4];
      av[0] = As[ty * 4 + 0][kk];
      av[1] = As[ty * 4 + 1][kk];
      av[2] = As[ty * 4 + 2][kk];
      av[3] = As[ty * 4 + 3][kk];
      float4 b4 = *(const float4*)&Bs[kk][tx << 2];
      float bv[4] = {b4.x, b4.y, b4.z, b4.w};
#pragma unroll
      for (int i = 0; i < 4; i++)
#pragma unroll
        for (int j = 0; j < 4; j++) acc[i][j] = fmaf(av[i], bv[j], acc[i][j]);
    }
    __syncthreads();
  }
#pragma unroll
  for (int i = 0; i < 4; i++) {
    float4 v = {acc[i][0], acc[i][1], acc[i][2], acc[i][3]};
    *(float4*)(C + (size_t)(row0 + ty * 4 + i) * N + (col0 + (tx << 2))) = v;
  }
}

// ---------------- GCN aggregate + self + bias + relu ----------------
__global__ __launch_bounds__(256) void k_gcn_combine(
    const float* __restrict__ hlin, const int* __restrict__ srcSorted,
    const float* __restrict__ dcoef, const int* __restrict__ rowStart,
    const float* __restrict__ dinv, const float* __restrict__ invdeg,
    const float* __restrict__ bias, float* __restrict__ hout, int N, int C, int shift) {
  int gid = blockIdx.x * blockDim.x + threadIdx.x;
  int n = gid >> shift;
  if (n >= N) return;
  int cq = (gid & ((1 << shift) - 1)) << 2;
  int e0 = rowStart[n], e1 = rowStart[n + 1];
  float di = dinv[n];
  float ax = 0.f, ay = 0.f, az = 0.f, aw = 0.f;
  for (int e = e0; e < e1; e++) {
    int s = srcSorted[e];
    float coef = dcoef[e] * di;
    float4 v = *(const float4*)(hlin + (size_t)s * C + cq);
    ax = fmaf(coef, v.x, ax);
    ay = fmaf(coef, v.y, ay);
    az = fmaf(coef, v.z, az);
    aw = fmaf(coef, v.w, aw);
  }
  float idg = invdeg[n];
  float4 hv = *(const float4*)(hlin + (size_t)n * C + cq);
  float4 bv = *(const float4*)(bias + cq);
  float4 r;
  r.x = fmaxf(fmaf(hv.x, idg, ax) + bv.x, 0.f);
  r.y = fmaxf(fmaf(hv.y, idg, ay) + bv.y, 0.f);
  r.z = fmaxf(fmaf(hv.z, idg, az) + bv.z, 0.f);
  r.w = fmaxf(fmaf(hv.w, idg, aw) + bv.w, 0.f);
  *(float4*)(hout + (size_t)n * C + cq) = r;
}

// ---------------- segment mean: one graph per block, 256 threads ----------------
__global__ __launch_bounds__(256) void k_segmean(const float* __restrict__ h2,
                                                 const int* __restrict__ starts,
                                                 float* __restrict__ emb) {
  __shared__ float tmp[128];
  int g = blockIdx.x;
  int t = threadIdx.x;
  int c = t & 127;
  int half = t >> 7;  // 0 or 1
  int s0 = starts[g], s1 = starts[g + 1];
  float inv = 1.0f / (float)(s1 - s0 > 0 ? s1 - s0 : 1);
  float sum = 0.f;
  for (int i = s0 + half; i < s1; i += 2) sum += h2[(size_t)i * 128 + c];
  if (half == 0) tmp[c] = sum;
  __syncthreads();
  if (half == 1) emb[(size_t)g * 128 + c] = (tmp[c] + sum) * inv;
}

// ---------------- VQC in registers: one wave per graph ----------------
// state index idx = (lane<<4) | j ; qubit w acts on idx bit B = 9-w.
// B>=4 -> lane bit (shfl_xor); B<=3 -> register bit (unrolled pairs).

template <int B>
__device__ __forceinline__ void ry_reg(float* st, float c, float s) {
#pragma unroll
  for (int j = 0; j < 16; j++) {
    if (!(j & (1 << B))) {
      float x0 = st[j], x1 = st[j | (1 << B)];
      st[j] = c * x0 - s * x1;
      st[j | (1 << B)] = fmaf(s, x0, c * x1);
    }
  }
}

template <int LB>
__device__ __forceinline__ void ry_lane(float* st, float c, float s, int lane) {
  bool hi = (lane >> LB) & 1;
#pragma unroll
  for (int j = 0; j < 16; j++) {
    float p = __shfl_xor(st[j], 1 << LB, 64);
    float a = c * st[j] - s * p;
    float b = fmaf(s, p, c * st[j]);
    st[j] = hi ? b : a;
  }
}

template <int LC, int LT>
__device__ __forceinline__ void cry_ll(float* st, float c, float s, int lane) {
  bool ctrl = (lane >> LC) & 1;
  bool hi = (lane >> LT) & 1;
#pragma unroll
  for (int j = 0; j < 16; j++) {
    float p = __shfl_xor(st[j], 1 << LT, 64);
    float a = c * st[j] - s * p;
    float b = fmaf(s, p, c * st[j]);
    float nv = hi ? b : a;
    st[j] = ctrl ? nv : st[j];
  }
}

__device__ __forceinline__ void cry_l0r3(float* st, float c, float s, int lane) {
  bool ctrl = lane & 1;
#pragma unroll
  for (int j = 0; j < 8; j++) {
    float x0 = st[j], x1 = st[j + 8];
    float n0 = c * x0 - s * x1;
    float n1 = fmaf(s, x0, c * x1);
    st[j] = ctrl ? n0 : x0;
    st[j + 8] = ctrl ? n1 : x1;
  }
}

template <int BC, int BT>
__device__ __forceinline__ void cry_rr(float* st, float c, float s) {
#pragma unroll
  for (int j = 0; j < 16; j++) {
    if ((j & (1 << BC)) && !(j & (1 << BT))) {
      float x0 = st[j], x1 = st[j | (1 << BT)];
      st[j] = c * x0 - s * x1;
      st[j | (1 << BT)] = fmaf(s, x0, c * x1);
    }
  }
}

#define RY_LAYER(base)                                    \
  ry_lane<5>(st, csc[(base) + 0], css[(base) + 0], lane); \
  ry_lane<4>(st, csc[(base) + 1], css[(base) + 1], lane); \
  ry_lane<3>(st, csc[(base) + 2], css[(base) + 2], lane); \
  ry_lane<2>(st, csc[(base) + 3], css[(base) + 3], lane); \
  ry_lane<1>(st, csc[(base) + 4], css[(base) + 4], lane); \
  ry_lane<0>(st, csc[(base) + 5], css[(base) + 5], lane); \
  ry_reg<3>(st, csc[(base) + 6], css[(base) + 6]);        \
  ry_reg<2>(st, csc[(base) + 7], css[(base) + 7]);        \
  ry_reg<1>(st, csc[(base) + 8], css[(base) + 8]);        \
  ry_reg<0>(st, csc[(base) + 9], css[(base) + 9]);

#define CRY_LAYER()                            \
  cry_ll<5, 4>(st, csc[50], css[50], lane);    \
  cry_ll<4, 3>(st, csc[51], css[51], lane);    \
  cry_ll<3, 2>(st, csc[52], css[52], lane);    \
  cry_ll<2, 1>(st, csc[53], css[53], lane);    \
  cry_ll<1, 0>(st, csc[54], css[54], lane);    \
  cry_l0r3(st, csc[55], css[55], lane);        \
  cry_rr<3, 2>(st, csc[56], css[56]);          \
  cry_rr<2, 1>(st, csc[57], css[57]);          \
  cry_rr<1, 0>(st, csc[58], css[58]);

__global__ __launch_bounds__(64) void k_vqc_head(
    const float* __restrict__ emb, const float* __restrict__ part,
    const float* __restrict__ projW, const float* __restrict__ projb,
    const float* __restrict__ vqcW, const float* __restrict__ epW,
    const float* __restrict__ epb, const float* __restrict__ cW1,
    const float* __restrict__ cb1, const float* __restrict__ cW2,
    const float* __restrict__ cb2, float* __restrict__ out) {
  int g = blockIdx.x;
  int lane = threadIdx.x;
  __shared__ float semb[128];
  __shared__ float csc[59], css[59];
  __shared__ float pool[5];
  __shared__ float zq[NQ];
  __shared__ float hid[16];

  {
    float2 v = *(const float2*)(emb + (size_t)g * 128 + lane * 2);
    semb[lane * 2] = v.x;
    semb[lane * 2 + 1] = v.y;
  }

  // reduce PB=64 edge-pool partials (lane b owns partial b)
  {
    const float* pp = part + (size_t)lane * 5120 + g * 5;
    float p0 = pp[0], p1 = pp[1], p2 = pp[2], p3 = pp[3], p4 = pp[4];
#pragma unroll
    for (int off = 32; off >= 1; off >>= 1) {
      p0 += __shfl_down(p0, off, 64);
      p1 += __shfl_down(p1, off, 64);
      p2 += __shfl_down(p2, off, 64);
      p3 += __shfl_down(p3, off, 64);
      p4 += __shfl_down(p4, off, 64);
    }
    if (lane == 0) {
      pool[0] = p0; pool[1] = p1; pool[2] = p2; pool[3] = p3; pool[4] = p4;
    }
  }
  __syncthreads();

  if (lane < NQ) {
    float sum = projb[lane];
    for (int k = 0; k < 128; k++) sum = fmaf(semb[k], projW[k * NQ + lane], sum);
    float th = tanhf(sum) * PI_F * 0.5f;
    csc[lane] = cosf(th);
    css[lane] = sinf(th);
  } else if (lane < 50) {
    float th = vqcW[lane - NQ] * 0.5f;
    csc[lane] = cosf(th);
    css[lane] = sinf(th);
  } else if (lane < 59) {
    int i = lane - 50;
    float icnt = 1.0f / fmaxf(pool[4], 1.0f);
    float sum = epb[i];
    for (int j = 0; j < 4; j++) sum = fmaf(pool[j] * icnt, epW[j * 9 + i], sum);
    float th = sum * 0.5f;
    csc[lane] = cosf(th);
    css[lane] = sinf(th);
  }
  __syncthreads();

  float st[16];
#pragma unroll
  for (int j = 0; j < 16; j++) st[j] = 0.f;
  if (lane == 0) st[0] = 1.f;

  RY_LAYER(0);
  RY_LAYER(10); CRY_LAYER();
  RY_LAYER(20); CRY_LAYER();
  RY_LAYER(30); CRY_LAYER();
  RY_LAYER(40); CRY_LAYER();

  // Z expectations: sign on idx bit B = 9-i (lane bit if B>=4)
  float p[16];
  float tot = 0.f;
#pragma unroll
  for (int j = 0; j < 16; j++) {
    p[j] = st[j] * st[j];
    tot += p[j];
  }
  float z[NQ];
#pragma unroll
  for (int i = 0; i < 6; i++) {
    int LB = 5 - i;
    z[i] = ((lane >> LB) & 1) ? -tot : tot;
  }
#pragma unroll
  for (int i = 6; i < 10; i++) {
    int B = 9 - i;
    float a = 0.f;
#pragma unroll
    for (int j = 0; j < 16; j++) a += ((j >> B) & 1) ? -p[j] : p[j];
    z[i] = a;
  }
#pragma unroll
  for (int off = 32; off >= 1; off >>= 1)
#pragma unroll
    for (int i = 0; i < 10; i++) z[i] += __shfl_down(z[i], off, 64);
  if (lane == 0) {
#pragma unroll
    for (int i = 0; i < 10; i++) zq[i] = z[i];
  }
  __syncthreads();

  if (lane < 16) {
    float sum = cb1[lane];
    for (int k = 0; k < 128; k++) sum = fmaf(semb[k], cW1[k * 16 + lane], sum);
#pragma unroll
    for (int k = 0; k < 10; k++) sum = fmaf(zq[k], cW1[(128 + k) * 16 + lane], sum);
    hid[lane] = fmaxf(sum, 0.f);
  }
  __syncthreads();
  if (lane == 0) {
    float sum = cb2[0];
#pragma unroll
    for (int j = 0; j < 16; j++) sum = fmaf(hid[j], cW2[j], sum);
    out[g] = sum;
  }
}

extern "C" void kernel_launch(void* const* d_in, const int* in_sizes, int n_in,
                              void* d_out, int out_size, void* d_ws, size_t ws_size,
                              hipStream_t stream) {
  const float* x = (const float*)d_in[0];
  const int* ei = (const int*)d_in[1];
  const int* batch = (const int*)d_in[2];
  const float* eattr = (const float*)d_in[3];
  const float* W1 = (const float*)d_in[4];
  const float* b1 = (const float*)d_in[5];
  const float* W2 = (const float*)d_in[6];
  const float* b2 = (const float*)d_in[7];
  const float* projW = (const float*)d_in[8];
  const float* projb = (const float*)d_in[9];
  const float* vqcW = (const float*)d_in[10];
  const float* epW = (const float*)d_in[11];
  const float* epb = (const float*)d_in[12];
  const float* cW1 = (const float*)d_in[13];
  const float* cb1 = (const float*)d_in[14];
  const float* cW2 = (const float*)d_in[15];
  const float* cb2 = (const float*)d_in[16];
  float* out = (float*)d_out;

  const int N = in_sizes[0] / 128;  // 32768
  const int E = in_sizes[1] / 2;    // 131072
  const int Bn = out_size;          // 1024

  const int* srcA = ei;
  const int* dstA = ei + E;

  char* ws = (char*)d_ws;
  float* bufA = (float*)ws;                         // 32 MB
  float* bufB = (float*)(ws + ((size_t)32 << 20));  // 32 MB
  size_t off = (size_t)64 << 20;
  auto alloc = [&](size_t bytes) {
    size_t o = off;
    off += (bytes + 255) & ~(size_t)255;
    return o;
  };
  int* cnt = (int*)(ws + alloc((size_t)N * 4));
  size_t zeroEnd = off;
  float* part = (float*)(ws + alloc((size_t)PB * 5120 * 4));
  int* rowStart = (int*)(ws + alloc((size_t)(N + 1) * 4));
  int* pos = (int*)(ws + alloc((size_t)N * 4));
  int* srcSorted = (int*)(ws + alloc((size_t)E * 4));
  float* dcoef = (float*)(ws + alloc((size_t)E * 4));
  float* dinv = (float*)(ws + alloc((size_t)N * 4));
  float* invdeg = (float*)(ws + alloc((size_t)N * 4));
  int* starts = (int*)(ws + alloc((size_t)(Bn + 1) * 4));
  int* incl = (int*)(ws + alloc((size_t)N * 4));
  int* bsum = (int*)(ws + alloc(64 * 4));
  float* emb = (float*)(ws + alloc((size_t)Bn * 128 * 4));

  int eblocks = (E + 255) / 256;
  int nblocks = (N + 255) / 256;
  int nb1024 = N >> 10;  // 32

  int zero4 = (int)((zeroEnd - ((size_t)64 << 20)) / 16);
  k_zero<<<(zero4 + 255) / 256, 256, 0, stream>>>((float4*)(ws + ((size_t)64 << 20)), zero4);

  k_count<<<eblocks, 256, 0, stream>>>(dstA, E, cnt);
  k_edge_pool<<<PB, 1024, 0, stream>>>(srcA, batch, eattr, E, part);
  k_scan1<<<nb1024, 1024, 0, stream>>>(cnt, incl, bsum);
  k_node_setup<<<nblocks, 256, 0, stream>>>(cnt, incl, bsum, batch, N, Bn, rowStart, pos,
                                            dinv, invdeg, starts);
  k_fill<<<eblocks, 256, 0, stream>>>(dstA, srcA, dinv, E, pos, srcSorted, dcoef);

  {
    dim3 grid(256 / 64, N / 64);
    k_gemm<<<grid, 256, 0, stream>>>(x, W1, bufA, N, 128, 256);
  }
  k_gcn_combine<<<(N * 64) / 256, 256, 0, stream>>>(bufA, srcSorted, dcoef, rowStart,
                                                    dinv, invdeg, b1, bufB, N, 256, 6);
  {
    dim3 grid(128 / 64, N / 64);
    k_gemm<<<grid, 256, 0, stream>>>(bufB, W2, bufA, N, 256, 128);
  }
  k_gcn_combine<<<(N * 32) / 256, 256, 0, stream>>>(bufA, srcSorted, dcoef, rowStart,
                                                    dinv, invdeg, b2, bufB, N, 128, 5);
  k_segmean<<<Bn, 256, 0, stream>>>(bufB, starts, emb);
  k_vqc_head<<<Bn, 64, 0, stream>>>(emb, part, projW, projb, vqcW, epW, epb,
                                    cW1, cb1, cW2, cb2, out);
}

// Round 8
// 199.659 us; speedup vs baseline: 1.0118x; 1.0118x over previous
//
#include <hip/hip_runtime.h>

#define PI_F 3.14159f
#define NQ 10
#define PB 64  // partial blocks for edge pooling

// ---------------- zero the accumulator region ----------------
__global__ void k_zero(float4* __restrict__ p, int n4) {
  int i = blockIdx.x * blockDim.x + threadIdx.x;
  int stride = gridDim.x * blockDim.x;
  float4 z = {0.f, 0.f, 0.f, 0.f};
  for (; i < n4; i += stride) p[i] = z;
}

// ---------------- dst-degree histogram (1 atomic/edge) ----------------
__global__ void k_count(const int* __restrict__ dstA, int E, int* __restrict__ cnt) {
  int e = blockIdx.x * blockDim.x + threadIdx.x;
  if (e < E) atomicAdd(&cnt[dstA[e]], 1);
}

// ---------------- edge-attr pooling: LDS bins + block partials ----------------
__global__ __launch_bounds__(1024) void k_edge_pool(const int* __restrict__ srcA,
                                                    const int* __restrict__ batch,
                                                    const float* __restrict__ eattr, int E,
                                                    float* __restrict__ part) {
  __shared__ float bins[1024 * 5];
  int t = threadIdx.x;
  for (int i = t; i < 5120; i += 1024) bins[i] = 0.f;
  __syncthreads();
  int per = (E + gridDim.x - 1) / gridDim.x;
  int base = blockIdx.x * per;
  int end = min(base + per, E);
  for (int e = base + t; e < end; e += 1024) {
    int s = srcA[e];
    int g = batch[s];
    float4 v = *(const float4*)(eattr + (size_t)e * 4);
    atomicAdd(&bins[g * 5 + 0], v.x);
    atomicAdd(&bins[g * 5 + 1], v.y);
    atomicAdd(&bins[g * 5 + 2], v.z);
    atomicAdd(&bins[g * 5 + 3], v.w);
    atomicAdd(&bins[g * 5 + 4], 1.0f);
  }
  __syncthreads();
  float* dst = part + (size_t)blockIdx.x * 5120;
  for (int i = t; i < 5120; i += 1024) dst[i] = bins[i];
}

// ---------------- scan level 1 ----------------
__global__ __launch_bounds__(1024) void k_scan1(const int* __restrict__ cnt,
                                                int* __restrict__ incl,
                                                int* __restrict__ bsum) {
  __shared__ int buf[1024];
  int t = threadIdx.x;
  int base = blockIdx.x << 10;
  buf[t] = cnt[base + t];
  __syncthreads();
#pragma unroll
  for (int off = 1; off < 1024; off <<= 1) {
    int x = (t >= off) ? buf[t - off] : 0;
    __syncthreads();
    buf[t] += x;
    __syncthreads();
  }
  incl[base + t] = buf[t];
  if (t == 1023) bsum[blockIdx.x] = buf[t];
}

// ---------------- node setup ----------------
__global__ void k_node_setup(const int* __restrict__ cnt, const int* __restrict__ incl,
                             const int* __restrict__ bsum, const int* __restrict__ batch,
                             int N, int Bn, int* __restrict__ rowStart,
                             int* __restrict__ pos, float* __restrict__ dinv,
                             float* __restrict__ invdeg, int* __restrict__ starts) {
  int i = blockIdx.x * blockDim.x + threadIdx.x;
  if (i >= N) return;
  int blk = i >> 10;
  int pre = 0;
  for (int j = 0; j < blk; j++) pre += bsum[j];
  int c = cnt[i];
  int inc = incl[i] + pre;
  rowStart[i + 1] = inc;
  pos[i] = inc - c;
  if (i == 0) rowStart[0] = 0;
  float d = (float)c + 1.0f;
  dinv[i] = 1.0f / sqrtf(d);
  invdeg[i] = 1.0f / d;
  int b = batch[i];
  int bp = (i == 0) ? -1 : batch[i - 1];
  for (int g = bp + 1; g <= b; g++) starts[g] = i;
  if (i == N - 1) {
    for (int g = b + 1; g <= Bn; g++) starts[g] = N;
  }
}

// ---------------- fill ----------------
__global__ void k_fill(const int* __restrict__ dst, const int* __restrict__ srcA,
                       const float* __restrict__ dinv, int E, int* __restrict__ pos,
                       int* __restrict__ srcSorted, float* __restrict__ dcoef) {
  int e = blockIdx.x * blockDim.x + threadIdx.x;
  if (e >= E) return;
  int s = srcA[e];
  int slot = atomicAdd(&pos[dst[e]], 1);
  srcSorted[slot] = s;
  dcoef[slot] = dinv[s];
}

// ---------------- fp32 tiled GEMM ----------------
__global__ __launch_bounds__(256) void k_gemm(const float* __restrict__ A,
                                              const float* __restrict__ B,
                                              float* __restrict__ C,
                                              int M, int K, int N) {
  __shared__ float As[64][36];
  __shared__ float Bs[32][68];
  int t = threadIdx.x;
  int tx = t & 15, ty = t >> 4;
  int row0 = blockIdx.y * 64, col0 = blockIdx.x * 64;
  float acc[4][4] = {};
  for (int k0 = 0; k0 < K; k0 += 32) {
#pragma unroll
    for (int rep = 0; rep < 2; rep++) {
      int slot = t + rep * 256;
      int r = slot >> 3;
      int cg = (slot & 7) << 2;
      float4 v = *(const float4*)(A + (size_t)(row0 + r) * K + (k0 + cg));
      *(float4*)&As[r][cg] = v;
      int r2 = slot >> 4;
      int cg2 = (slot & 15) << 2;
      float4 w = *(const float4*)(B + (size_t)(k0 + r2) * N + (col0 + cg2));
      *(float4*)&Bs[r2][cg2] = w;
    }
    __syncthreads();
#pragma unroll
    for (int kk = 0; kk < 32; kk++) {
      float av[4];
      av[0] = As[ty * 4 + 0][kk];
      av[1] = As[ty * 4 + 1][kk];
      av[2] = As[ty * 4 + 2][kk];
      av[3] = As[ty * 4 + 3][kk];
      float4 b4 = *(const float4*)&Bs[kk][tx << 2];
      float bv[4] = {b4.x, b4.y, b4.z, b4.w};
#pragma unroll
      for (int i = 0; i < 4; i++)
#pragma unroll
        for (int j = 0; j < 4; j++) acc[i][j] = fmaf(av[i], bv[j], acc[i][j]);
    }
    __syncthreads();
  }
#pragma unroll
  for (int i = 0; i < 4; i++) {
    float4 v = {acc[i][0], acc[i][1], acc[i][2], acc[i][3]};
    *(float4*)(C + (size_t)(row0 + ty * 4 + i) * N + (col0 + (tx << 2))) = v;
  }
}

// ---------------- GCN aggregate + self + bias + relu ----------------
__global__ __launch_bounds__(256) void k_gcn_combine(
    const float* __restrict__ hlin, const int* __restrict__ srcSorted,
    const float* __restrict__ dcoef, const int* __restrict__ rowStart,
    const float* __restrict__ dinv, const float* __restrict__ invdeg,
    const float* __restrict__ bias, float* __restrict__ hout, int N, int C, int shift) {
  int gid = blockIdx.x * blockDim.x + threadIdx.x;
  int n = gid >> shift;
  if (n >= N) return;
  int cq = (gid & ((1 << shift) - 1)) << 2;
  int e0 = rowStart[n], e1 = rowStart[n + 1];
  float di = dinv[n];
  float ax = 0.f, ay = 0.f, az = 0.f, aw = 0.f;
  for (int e = e0; e < e1; e++) {
    int s = srcSorted[e];
    float coef = dcoef[e] * di;
    float4 v = *(const float4*)(hlin + (size_t)s * C + cq);
    ax = fmaf(coef, v.x, ax);
    ay = fmaf(coef, v.y, ay);
    az = fmaf(coef, v.z, az);
    aw = fmaf(coef, v.w, aw);
  }
  float idg = invdeg[n];
  float4 hv = *(const float4*)(hlin + (size_t)n * C + cq);
  float4 bv = *(const float4*)(bias + cq);
  float4 r;
  r.x = fmaxf(fmaf(hv.x, idg, ax) + bv.x, 0.f);
  r.y = fmaxf(fmaf(hv.y, idg, ay) + bv.y, 0.f);
  r.z = fmaxf(fmaf(hv.z, idg, az) + bv.z, 0.f);
  r.w = fmaxf(fmaf(hv.w, idg, aw) + bv.w, 0.f);
  *(float4*)(hout + (size_t)n * C + cq) = r;
}

// ---------------- segment mean: one graph per block, 256 threads ----------------
__global__ __launch_bounds__(256) void k_segmean(const float* __restrict__ h2,
                                                 const int* __restrict__ starts,
                                                 float* __restrict__ emb) {
  __shared__ float tmp[128];
  int g = blockIdx.x;
  int t = threadIdx.x;
  int c = t & 127;
  int half = t >> 7;  // 0 or 1
  int s0 = starts[g], s1 = starts[g + 1];
  float inv = 1.0f / (float)(s1 - s0 > 0 ? s1 - s0 : 1);
  float sum = 0.f;
  for (int i = s0 + half; i < s1; i += 2) sum += h2[(size_t)i * 128 + c];
  if (half == 0) tmp[c] = sum;
  __syncthreads();
  if (half == 1) emb[(size_t)g * 128 + c] = (tmp[c] + sum) * inv;
}

// ---------------- angle precompute: 11 waves per graph ----------------
// wave a<10: proj angle for qubit a (128-dot over 64 lanes).
// wave a==10: pool-reduce part + all 9 ep angles.
__global__ __launch_bounds__(256) void k_angles(
    const float* __restrict__ emb, const float* __restrict__ part,
    const float* __restrict__ projW, const float* __restrict__ projb,
    const float* __restrict__ epW, const float* __restrict__ epb, int Bn,
    float* __restrict__ angc, float* __restrict__ angs) {
  int wid = (blockIdx.x * blockDim.x + threadIdx.x) >> 6;
  int lane = threadIdx.x & 63;
  int g = wid / 11;
  int a = wid - g * 11;
  if (g >= Bn) return;
  if (a < 10) {
    float2 v = *(const float2*)(emb + (size_t)g * 128 + lane * 2);
    float s = v.x * projW[(lane * 2) * NQ + a] + v.y * projW[(lane * 2 + 1) * NQ + a];
#pragma unroll
    for (int off = 32; off >= 1; off >>= 1) s += __shfl_down(s, off, 64);
    if (lane == 0) {
      float th = tanhf(s + projb[a]) * PI_F * 0.5f;
      angc[g * 19 + a] = cosf(th);
      angs[g * 19 + a] = sinf(th);
    }
  } else {
    const float* pp = part + (size_t)lane * 5120 + g * 5;
    float p0 = pp[0], p1 = pp[1], p2 = pp[2], p3 = pp[3], p4 = pp[4];
#pragma unroll
    for (int off = 32; off >= 1; off >>= 1) {
      p0 += __shfl_down(p0, off, 64);
      p1 += __shfl_down(p1, off, 64);
      p2 += __shfl_down(p2, off, 64);
      p3 += __shfl_down(p3, off, 64);
      p4 += __shfl_down(p4, off, 64);
    }
    p0 = __shfl(p0, 0, 64);
    p1 = __shfl(p1, 0, 64);
    p2 = __shfl(p2, 0, 64);
    p3 = __shfl(p3, 0, 64);
    p4 = __shfl(p4, 0, 64);
    if (lane < 9) {
      float icnt = 1.0f / fmaxf(p4, 1.0f);
      float sum = epb[lane];
      sum = fmaf(p0 * icnt, epW[0 * 9 + lane], sum);
      sum = fmaf(p1 * icnt, epW[1 * 9 + lane], sum);
      sum = fmaf(p2 * icnt, epW[2 * 9 + lane], sum);
      sum = fmaf(p3 * icnt, epW[3 * 9 + lane], sum);
      float th = sum * 0.5f;
      angc[g * 19 + 10 + lane] = cosf(th);
      angs[g * 19 + 10 + lane] = sinf(th);
    }
  }
}

// ---------------- VQC in registers: one wave per graph ----------------
template <int B>
__device__ __forceinline__ void ry_reg(float* st, float c, float s) {
#pragma unroll
  for (int j = 0; j < 16; j++) {
    if (!(j & (1 << B))) {
      float x0 = st[j], x1 = st[j | (1 << B)];
      st[j] = c * x0 - s * x1;
      st[j | (1 << B)] = fmaf(s, x0, c * x1);
    }
  }
}

template <int LB>
__device__ __forceinline__ void ry_lane(float* st, float c, float s, int lane) {
  bool hi = (lane >> LB) & 1;
#pragma unroll
  for (int j = 0; j < 16; j++) {
    float p = __shfl_xor(st[j], 1 << LB, 64);
    float a = c * st[j] - s * p;
    float b = fmaf(s, p, c * st[j]);
    st[j] = hi ? b : a;
  }
}

template <int LC, int LT>
__device__ __forceinline__ void cry_ll(float* st, float c, float s, int lane) {
  bool ctrl = (lane >> LC) & 1;
  bool hi = (lane >> LT) & 1;
#pragma unroll
  for (int j = 0; j < 16; j++) {
    float p = __shfl_xor(st[j], 1 << LT, 64);
    float a = c * st[j] - s * p;
    float b = fmaf(s, p, c * st[j]);
    float nv = hi ? b : a;
    st[j] = ctrl ? nv : st[j];
  }
}

__device__ __forceinline__ void cry_l0r3(float* st, float c, float s, int lane) {
  bool ctrl = lane & 1;
#pragma unroll
  for (int j = 0; j < 8; j++) {
    float x0 = st[j], x1 = st[j + 8];
    float n0 = c * x0 - s * x1;
    float n1 = fmaf(s, x0, c * x1);
    st[j] = ctrl ? n0 : x0;
    st[j + 8] = ctrl ? n1 : x1;
  }
}

template <int BC, int BT>
__device__ __forceinline__ void cry_rr(float* st, float c, float s) {
#pragma unroll
  for (int j = 0; j < 16; j++) {
    if ((j & (1 << BC)) && !(j & (1 << BT))) {
      float x0 = st[j], x1 = st[j | (1 << BT)];
      st[j] = c * x0 - s * x1;
      st[j | (1 << BT)] = fmaf(s, x0, c * x1);
    }
  }
}

#define RY_LAYER(base)                                    \
  ry_lane<5>(st, csc[(base) + 0], css[(base) + 0], lane); \
  ry_lane<4>(st, csc[(base) + 1], css[(base) + 1], lane); \
  ry_lane<3>(st, csc[(base) + 2], css[(base) + 2], lane); \
  ry_lane<2>(st, csc[(base) + 3], css[(base) + 3], lane); \
  ry_lane<1>(st, csc[(base) + 4], css[(base) + 4], lane); \
  ry_lane<0>(st, csc[(base) + 5], css[(base) + 5], lane); \
  ry_reg<3>(st, csc[(base) + 6], css[(base) + 6]);        \
  ry_reg<2>(st, csc[(base) + 7], css[(base) + 7]);        \
  ry_reg<1>(st, csc[(base) + 8], css[(base) + 8]);        \
  ry_reg<0>(st, csc[(base) + 9], css[(base) + 9]);

#define CRY_LAYER()                            \
  cry_ll<5, 4>(st, csc[50], css[50], lane);    \
  cry_ll<4, 3>(st, csc[51], css[51], lane);    \
  cry_ll<3, 2>(st, csc[52], css[52], lane);    \
  cry_ll<2, 1>(st, csc[53], css[53], lane);    \
  cry_ll<1, 0>(st, csc[54], css[54], lane);    \
  cry_l0r3(st, csc[55], css[55], lane);        \
  cry_rr<3, 2>(st, csc[56], css[56]);          \
  cry_rr<2, 1>(st, csc[57], css[57]);          \
  cry_rr<1, 0>(st, csc[58], css[58]);

__global__ __launch_bounds__(64) void k_vqc_head(
    const float* __restrict__ emb, const float* __restrict__ angc,
    const float* __restrict__ angs, const float* __restrict__ vqcW,
    const float* __restrict__ cW1, const float* __restrict__ cb1,
    const float* __restrict__ cW2, const float* __restrict__ cb2,
    float* __restrict__ out) {
  int g = blockIdx.x;
  int lane = threadIdx.x;
  __shared__ float semb[128];
  __shared__ float csc[59], css[59];
  __shared__ float zq[NQ];

  {
    float2 v = *(const float2*)(emb + (size_t)g * 128 + lane * 2);
    semb[lane * 2] = v.x;
    semb[lane * 2 + 1] = v.y;
  }
  if (lane < NQ) {
    csc[lane] = angc[g * 19 + lane];
    css[lane] = angs[g * 19 + lane];
  } else if (lane < 50) {
    float th = vqcW[lane - NQ] * 0.5f;
    csc[lane] = cosf(th);
    css[lane] = sinf(th);
  } else if (lane < 59) {
    csc[lane] = angc[g * 19 + 10 + (lane - 50)];
    css[lane] = angs[g * 19 + 10 + (lane - 50)];
  }
  __syncthreads();

  float st[16];
#pragma unroll
  for (int j = 0; j < 16; j++) st[j] = 0.f;
  if (lane == 0) st[0] = 1.f;

  RY_LAYER(0);
  RY_LAYER(10); CRY_LAYER();
  RY_LAYER(20); CRY_LAYER();
  RY_LAYER(30); CRY_LAYER();
  RY_LAYER(40); CRY_LAYER();

  // Z expectations: sign on idx bit B = 9-i (lane bit if B>=4)
  float p[16];
  float tot = 0.f;
#pragma unroll
  for (int j = 0; j < 16; j++) {
    p[j] = st[j] * st[j];
    tot += p[j];
  }
  float z[NQ];
#pragma unroll
  for (int i = 0; i < 6; i++) {
    int LB = 5 - i;
    z[i] = ((lane >> LB) & 1) ? -tot : tot;
  }
#pragma unroll
  for (int i = 6; i < 10; i++) {
    int B = 9 - i;
    float a = 0.f;
#pragma unroll
    for (int j = 0; j < 16; j++) a += ((j >> B) & 1) ? -p[j] : p[j];
    z[i] = a;
  }
#pragma unroll
  for (int off = 32; off >= 1; off >>= 1)
#pragma unroll
    for (int i = 0; i < 10; i++) z[i] += __shfl_down(z[i], off, 64);
  if (lane == 0) {
#pragma unroll
    for (int i = 0; i < 10; i++) zq[i] = z[i];
  }
  __syncthreads();

  // head, lane-parallel: lane = chunk(c=lane>>4)*... o = lane&15
  int o = lane & 15, cch = lane >> 4;
  float sum = 0.f;
#pragma unroll
  for (int t = 0; t < 32; t++) {
    int k = cch * 32 + t;
    sum = fmaf(semb[k], cW1[k * 16 + o], sum);
  }
  if (cch == 3) {
#pragma unroll
    for (int k = 0; k < 10; k++) sum = fmaf(zq[k], cW1[(128 + k) * 16 + o], sum);
  }
  sum += __shfl_down(sum, 32, 64);
  sum += __shfl_down(sum, 16, 64);
  float hv = fmaxf(sum + cb1[o], 0.f);
  float ov = (lane < 16) ? hv * cW2[lane] : 0.f;
  ov += __shfl_down(ov, 8, 64);
  ov += __shfl_down(ov, 4, 64);
  ov += __shfl_down(ov, 2, 64);
  ov += __shfl_down(ov, 1, 64);
  if (lane == 0) out[g] = ov + cb2[0];
}

extern "C" void kernel_launch(void* const* d_in, const int* in_sizes, int n_in,
                              void* d_out, int out_size, void* d_ws, size_t ws_size,
                              hipStream_t stream) {
  const float* x = (const float*)d_in[0];
  const int* ei = (const int*)d_in[1];
  const int* batch = (const int*)d_in[2];
  const float* eattr = (const float*)d_in[3];
  const float* W1 = (const float*)d_in[4];
  const float* b1 = (const float*)d_in[5];
  const float* W2 = (const float*)d_in[6];
  const float* b2 = (const float*)d_in[7];
  const float* projW = (const float*)d_in[8];
  const float* projb = (const float*)d_in[9];
  const float* vqcW = (const float*)d_in[10];
  const float* epW = (const float*)d_in[11];
  const float* epb = (const float*)d_in[12];
  const float* cW1 = (const float*)d_in[13];
  const float* cb1 = (const float*)d_in[14];
  const float* cW2 = (const float*)d_in[15];
  const float* cb2 = (const float*)d_in[16];
  float* out = (float*)d_out;

  const int N = in_sizes[0] / 128;  // 32768
  const int E = in_sizes[1] / 2;    // 131072
  const int Bn = out_size;          // 1024

  const int* srcA = ei;
  const int* dstA = ei + E;

  char* ws = (char*)d_ws;
  float* bufA = (float*)ws;                         // 32 MB
  float* bufB = (float*)(ws + ((size_t)32 << 20));  // 32 MB
  size_t off = (size_t)64 << 20;
  auto alloc = [&](size_t bytes) {
    size_t o = off;
    off += (bytes + 255) & ~(size_t)255;
    return o;
  };
  int* cnt = (int*)(ws + alloc((size_t)N * 4));
  size_t zeroEnd = off;
  float* part = (float*)(ws + alloc((size_t)PB * 5120 * 4));
  int* rowStart = (int*)(ws + alloc((size_t)(N + 1) * 4));
  int* pos = (int*)(ws + alloc((size_t)N * 4));
  int* srcSorted = (int*)(ws + alloc((size_t)E * 4));
  float* dcoef = (float*)(ws + alloc((size_t)E * 4));
  float* dinv = (float*)(ws + alloc((size_t)N * 4));
  float* invdeg = (float*)(ws + alloc((size_t)N * 4));
  int* starts = (int*)(ws + alloc((size_t)(Bn + 1) * 4));
  int* incl = (int*)(ws + alloc((size_t)N * 4));
  int* bsum = (int*)(ws + alloc(64 * 4));
  float* emb = (float*)(ws + alloc((size_t)Bn * 128 * 4));
  float* angc = (float*)(ws + alloc((size_t)Bn * 19 * 4));
  float* angs = (float*)(ws + alloc((size_t)Bn * 19 * 4));

  int eblocks = (E + 255) / 256;
  int nblocks = (N + 255) / 256;
  int nb1024 = N >> 10;  // 32

  int zero4 = (int)((zeroEnd - ((size_t)64 << 20)) / 16);
  k_zero<<<(zero4 + 255) / 256, 256, 0, stream>>>((float4*)(ws + ((size_t)64 << 20)), zero4);

  k_count<<<eblocks, 256, 0, stream>>>(dstA, E, cnt);
  k_edge_pool<<<PB, 1024, 0, stream>>>(srcA, batch, eattr, E, part);
  k_scan1<<<nb1024, 1024, 0, stream>>>(cnt, incl, bsum);
  k_node_setup<<<nblocks, 256, 0, stream>>>(cnt, incl, bsum, batch, N, Bn, rowStart, pos,
                                            dinv, invdeg, starts);
  k_fill<<<eblocks, 256, 0, stream>>>(dstA, srcA, dinv, E, pos, srcSorted, dcoef);

  {
    dim3 grid(256 / 64, N / 64);
    k_gemm<<<grid, 256, 0, stream>>>(x, W1, bufA, N, 128, 256);
  }
  k_gcn_combine<<<(N * 64) / 256, 256, 0, stream>>>(bufA, srcSorted, dcoef, rowStart,
                                                    dinv, invdeg, b1, bufB, N, 256, 6);
  {
    dim3 grid(128 / 64, N / 64);
    k_gemm<<<grid, 256, 0, stream>>>(bufB, W2, bufA, N, 256, 128);
  }
  k_gcn_combine<<<(N * 32) / 256, 256, 0, stream>>>(bufA, srcSorted, dcoef, rowStart,
                                                    dinv, invdeg, b2, bufB, N, 128, 5);
  k_segmean<<<Bn, 256, 0, stream>>>(bufB, starts, emb);
  {
    int waves = Bn * 11;
    k_angles<<<(waves + 3) / 4, 256, 0, stream>>>(emb, part, projW, projb, epW, epb, Bn,
                                                  angc, angs);
  }
  k_vqc_head<<<Bn, 64, 0, stream>>>(emb, angc, angs, vqcW, cW1, cb1, cW2, cb2, out);
}